// Round 5
// baseline (111.042 us; speedup 1.0000x reference)
//
#include <hip/hip_runtime.h>

// WaveletLinear: y[b,o] = sum_i w[o,i] * (1 - s^2) * exp(-0.5 s^2),
//   s = (x[b,i] - t[o,i]) / (A_MIN + softplus(sr[o,i]) + EPS)
// Rework: u = K*s'^2 with s' = s*sqrt(K), K = 0.5*log2(e); e2 = exp2(-u);
//   y = sum_i (mwk*u + w) * e2,  mwk = -w/K     <- single-accumulator form
//
// R10: REVERT to R8's proven structure (R9's macro pipeline was broken;
// bug unfound -> discard, don't stack on unverified code). Single change:
// scalar v_fma_f32/v_mul_f32 asm instead of v_pk_*_f32. Rationale: R6/R7/R8
// all measured ~143 busy-cyc/step with nominally different mixes -- because
// R6's v2f builtins already compiled to pk ops; scalar f32 was never tested.
// HW-verified: v_fma_f32 = 2 cyc/wave64 (103 TF measured). If v_pk_fma_f32
// is half-rate per flop (8 cyc/inst), scalar = 64 cyc/step vs pk 128, and
// the 143 measured busy matches the pk=8cyc model. Scalar rewrite is >=
// neutral with ~1.4x upside on wl_main. Everything else byte-identical R8.

#define WL_A_MIN 0.001f
#define WL_EPS   1e-8f

constexpr int WL_B = 512;
constexpr int WL_O = 1024;
constexpr int WL_I = 512;

// K = 0.5*log2(e); sqrt(K); 1/K; log2(e); ln(2)
#define WL_SQK  0.84932180553704583800f
#define WL_IK   1.38629436111989061883f
#define WL_L2E  1.44269504088896340736f
#define WL_LN2  0.69314718055994530942f

typedef float v2f __attribute__((ext_vector_type(2)));

struct P3 { float nti, inv, w; };          // prep-internal LDS staging

__device__ __forceinline__ float fast_exp2(float a) {
#if __has_builtin(__builtin_amdgcn_exp2f)
    return __builtin_amdgcn_exp2f(a);
#else
    return exp2f(a);
#endif
}
__device__ __forceinline__ float fast_log2(float a) {
#if __has_builtin(__builtin_amdgcn_logf)
    return __builtin_amdgcn_logf(a);
#else
    return __log2f(a);
#endif
}
__device__ __forceinline__ float fast_rcp(float a) {
#if __has_builtin(__builtin_amdgcn_rcpf)
    return __builtin_amdgcn_rcpf(a);
#else
    return 1.0f / a;
#endif
}

// Param precompute. Block = 256 thr handles a 64(o) x 16(i) tile.
// Phase 1: coalesced float4 reads, compute, store P3 into LDS (transpose).
// Phase 2: lane=o writes A2[i][o]={nti,inv} (dwordx2) and W1[i][o]=w (dword).
__global__ __launch_bounds__(256) void wl_prep(
    const float* __restrict__ translation,
    const float* __restrict__ scale_raw,
    const float* __restrict__ weights,
    v2f* __restrict__ A2,
    float* __restrict__ W1)
{
    __shared__ P3 lds[16 * 64];                        // 12 KB  [i_l][o_l]
    const int t  = threadIdx.x;
    const int o0 = blockIdx.x * 64;
    const int i0 = blockIdx.y * 16;

    {
        const int o_l = t >> 2;                        // 0..63
        const int iq  = t & 3;                         // 0..3 -> 4 i each
        const size_t g = (size_t)(o0 + o_l) * WL_I + (i0 + iq * 4);
        const float4 tv = *reinterpret_cast<const float4*>(translation + g);
        const float4 sv = *reinterpret_cast<const float4*>(scale_raw   + g);
        const float4 wv = *reinterpret_cast<const float4*>(weights     + g);
        const float tt[4] = {tv.x, tv.y, tv.z, tv.w};
        const float ss[4] = {sv.x, sv.y, sv.z, sv.w};
        const float ww[4] = {wv.x, wv.y, wv.z, wv.w};
        #pragma unroll
        for (int j = 0; j < 4; ++j) {
            float ex  = fast_exp2(ss[j] * WL_L2E);     // softplus via hw exp2/log2
            float sp  = fast_log2(1.0f + ex) * WL_LN2;
            float inv = fast_rcp(WL_A_MIN + sp + WL_EPS) * WL_SQK;
            P3 pv; pv.nti = -tt[j] * inv; pv.inv = inv; pv.w = ww[j];
            lds[(iq * 4 + j) * 64 + o_l] = pv;
        }
    }
    __syncthreads();
    {
        const int o_l = t & 63;
        const int r   = t >> 6;                        // 0..3 -> 4 i each
        const int o   = o0 + o_l;
        #pragma unroll
        for (int j = 0; j < 4; ++j) {
            const int i_l = r * 4 + j;
            P3 a = lds[i_l * 64 + o_l];
            A2[(size_t)(i0 + i_l) * WL_O + o] = (v2f){a.nti, a.inv};
            W1[(size_t)(i0 + i_l) * WL_O + o] = a.w;
        }
    }
}

// Main: grid (O/64=16, B/8=64) = 1024 blocks, 512 thr = 8 waves.
// Wave wid = i-eighth (64 i); covers all 8 b of the tile.
// gx-major linear ids -> o-slab pinned to one XCD's L2 (param reuse).
__global__ __launch_bounds__(512, 8) void wl_main(
    const float* __restrict__ x,
    const v2f* __restrict__ A2,
    const float* __restrict__ W1,
    float* __restrict__ out)
{
    __shared__ float smem[8 * 513];                    // 16.4 KB (xT uses 16 KB)

    const int tid  = threadIdx.x;
    const int lane = tid & 63;
    const int wid  = tid >> 6;                         // 0..7 = i-eighth
    const int o    = blockIdx.x * 64 + lane;
    const int b0   = blockIdx.y * 8;

    // ---- stage x^T once: xT[i*8 + b_l]; one wave per b-row, coalesced ----
    {
        const int b_l = tid & 7;
        const int seg = tid >> 3;                      // 0..63 -> i in [seg*8,+8)
        const float* xg = &x[(size_t)(b0 + b_l) * WL_I + seg * 8];
        const float4 v0 = *reinterpret_cast<const float4*>(xg);
        const float4 v1 = *reinterpret_cast<const float4*>(xg + 4);
        const int base = seg * 64 + b_l;
        smem[base +  0] = v0.x;
        smem[base +  8] = v0.y;
        smem[base + 16] = v0.z;
        smem[base + 24] = v0.w;
        smem[base + 32] = v1.x;
        smem[base + 40] = v1.y;
        smem[base + 48] = v1.z;
        smem[base + 56] = v1.w;
    }
    __syncthreads();

    const v2f*   __restrict__ pA = A2 + (size_t)(wid * 64) * WL_O + o;
    const float* __restrict__ pW = W1 + (size_t)(wid * 64) * WL_O + o;
    const float* xr = &smem[wid * 64 * 8];             // uniform per wave

    float acc[8] = {0.f, 0.f, 0.f, 0.f, 0.f, 0.f, 0.f, 0.f};

    #pragma unroll 4
    for (int ii = 0; ii < 64; ++ii) {
        const v2f pa = *pA;  pA += WL_O;               // {nti, inv}  512B/wave
        const float w = *pW;  pW += WL_O;              // w           256B/wave
        const float mwk = w * (-WL_IK);                // 1 v_mul (literal src0)
        const float nti = pa.x, inv = pa.y;
        const float4 xa = ((const float4*)xr)[0];      // b0..3 (broadcast)
        const float4 xb = ((const float4*)xr)[1];      // b4..7 (broadcast)
        xr += 8;
        const float xs[8] = {xa.x, xa.y, xa.z, xa.w, xb.x, xb.y, xb.z, xb.w};
        #pragma unroll
        for (int b = 0; b < 8; ++b) {                  // scalar v_fma chain:
            float s_, u_, v_, e_;
            asm("v_fma_f32 %0, %1, %2, %3"             // s = x*inv + nti
                : "=v"(s_) : "v"(xs[b]), "v"(inv), "v"(nti));
            asm("v_mul_f32 %0, %1, %1"                 // u = s*s
                : "=v"(u_) : "v"(s_));
            e_ = fast_exp2(-u_);                       // e = exp2(-u)  (trans)
            asm("v_fma_f32 %0, %1, %2, %3"             // v = mwk*u + w
                : "=v"(v_) : "v"(mwk), "v"(u_), "v"(w));
            asm("v_fma_f32 %0, %1, %2, %0"             // acc += v*e
                : "+v"(acc[b]) : "v"(v_), "v"(e_));
        }
    }

    // ---- parallel epilogue: plane-major dump (conflict-free), 1 b per wave ----
    __syncthreads();                                   // done reading xT
    {
        const int c = wid * 64 + lane;                 // 0..511
        #pragma unroll
        for (int k = 0; k < 8; ++k)
            smem[k * 513 + c] = acc[k];                // lane-stride 4B: conflict-free
    }
    __syncthreads();
    {
        // wave wid handles b = b0 + wid (plane wid = y[b] partials)
        float y = 0.f;
        #pragma unroll
        for (int sw = 0; sw < 8; ++sw)
            y += smem[wid * 513 + sw * 64 + lane];
        out[(size_t)(b0 + wid) * WL_O + o] = y;
    }
}

extern "C" void kernel_launch(void* const* d_in, const int* in_sizes, int n_in,
                              void* d_out, int out_size, void* d_ws, size_t ws_size,
                              hipStream_t stream) {
    const float* x           = (const float*)d_in[0];
    const float* translation = (const float*)d_in[1];
    const float* scale_raw   = (const float*)d_in[2];
    const float* weights     = (const float*)d_in[3];
    float*       out         = (float*)d_out;
    // workspace: A2 pairs {nti,inv} 4.19MB, then W1 floats 2.10MB (6.3MB total)
    v2f*   A2 = (v2f*)d_ws;
    float* W1 = (float*)((char*)d_ws + (size_t)WL_I * WL_O * sizeof(v2f));

    wl_prep<<<dim3(WL_O / 64, WL_I / 16), dim3(256), 0, stream>>>(
        translation, scale_raw, weights, A2, W1);

    wl_main<<<dim3(WL_O / 64, WL_B / 8), dim3(512), 0, stream>>>(
        x, A2, W1, out);
}

// Round 6
// 104.564 us; speedup vs baseline: 1.0620x; 1.0620x over previous
//
#include <hip/hip_runtime.h>

// WaveletLinear: y[b,o] = sum_i w[o,i] * (1 - s^2) * exp(-0.5 s^2),
//   s = (x[b,i] - t[o,i]) / (A_MIN + softplus(sr[o,i]) + EPS)
// Rework: u = K*s'^2 with s' = s*sqrt(K), K = 0.5*log2(e); e2 = exp2(-u);
//   y = sum_i (mwk*u + w) * e2,  mwk = -w/K     <- single-accumulator form
//
// R11: latency-bound fix by SIZING (no asm pipeline). R8 vs R10 resolved the
// counters: VALUBusy is ~any-SIMD-of-CU activity; per-SIMD busy is only
// 20%(R8)/37%(R10) -- both kernels ~75% idle, wall 257 cyc/step vs ~50 busy.
// Latency-bound on the per-step param loads + uniform LDS reads with thin
// per-step compute and ~5 resident waves/SIMD. Changes:
//   1. b-tile 8 -> 16: 2x compute per param load (2x latency cover), and
//      total param L2 traffic HALVES (read by 32 b-blocks, not 64).
//   2. 1024-thr blocks, i split 16-way (32 i/wave): grid (16,32)=512 blocks
//      = exactly 2 blocks/CU = 32 waves/CU = full occupancy, no tail.
//   3. Indexed param loads (no pointer-bump chains) + unroll 4.
// XCD pinning kept: XCD = gx mod 8 -> 2 slabs (~786 KB) per XCD L2.
// Math = R10's verified scalar form in plain C (R6 showed codegen-equiv).

#define WL_A_MIN 0.001f
#define WL_EPS   1e-8f

constexpr int WL_B = 512;
constexpr int WL_O = 1024;
constexpr int WL_I = 512;

// K = 0.5*log2(e); sqrt(K); 1/K; log2(e); ln(2)
#define WL_SQK  0.84932180553704583800f
#define WL_IK   1.38629436111989061883f
#define WL_L2E  1.44269504088896340736f
#define WL_LN2  0.69314718055994530942f

typedef float v2f __attribute__((ext_vector_type(2)));

struct P3 { float nti, inv, w; };          // prep-internal LDS staging

__device__ __forceinline__ float fast_exp2(float a) {
#if __has_builtin(__builtin_amdgcn_exp2f)
    return __builtin_amdgcn_exp2f(a);
#else
    return exp2f(a);
#endif
}
__device__ __forceinline__ float fast_log2(float a) {
#if __has_builtin(__builtin_amdgcn_logf)
    return __builtin_amdgcn_logf(a);
#else
    return __log2f(a);
#endif
}
__device__ __forceinline__ float fast_rcp(float a) {
#if __has_builtin(__builtin_amdgcn_rcpf)
    return __builtin_amdgcn_rcpf(a);
#else
    return 1.0f / a;
#endif
}

// Param precompute (UNCHANGED from R10, verified). Block = 256 thr handles a
// 64(o) x 16(i) tile. Phase 1: coalesced float4 reads, compute, store P3 to
// LDS (transpose). Phase 2: lane=o writes A2[i][o]={nti,inv}, W1[i][o]=w.
__global__ __launch_bounds__(256) void wl_prep(
    const float* __restrict__ translation,
    const float* __restrict__ scale_raw,
    const float* __restrict__ weights,
    v2f* __restrict__ A2,
    float* __restrict__ W1)
{
    __shared__ P3 lds[16 * 64];                        // 12 KB  [i_l][o_l]
    const int t  = threadIdx.x;
    const int o0 = blockIdx.x * 64;
    const int i0 = blockIdx.y * 16;

    {
        const int o_l = t >> 2;                        // 0..63
        const int iq  = t & 3;                         // 0..3 -> 4 i each
        const size_t g = (size_t)(o0 + o_l) * WL_I + (i0 + iq * 4);
        const float4 tv = *reinterpret_cast<const float4*>(translation + g);
        const float4 sv = *reinterpret_cast<const float4*>(scale_raw   + g);
        const float4 wv = *reinterpret_cast<const float4*>(weights     + g);
        const float tt[4] = {tv.x, tv.y, tv.z, tv.w};
        const float ss[4] = {sv.x, sv.y, sv.z, sv.w};
        const float ww[4] = {wv.x, wv.y, wv.z, wv.w};
        #pragma unroll
        for (int j = 0; j < 4; ++j) {
            float ex  = fast_exp2(ss[j] * WL_L2E);     // softplus via hw exp2/log2
            float sp  = fast_log2(1.0f + ex) * WL_LN2;
            float inv = fast_rcp(WL_A_MIN + sp + WL_EPS) * WL_SQK;
            P3 pv; pv.nti = -tt[j] * inv; pv.inv = inv; pv.w = ww[j];
            lds[(iq * 4 + j) * 64 + o_l] = pv;
        }
    }
    __syncthreads();
    {
        const int o_l = t & 63;
        const int r   = t >> 6;                        // 0..3 -> 4 i each
        const int o   = o0 + o_l;
        #pragma unroll
        for (int j = 0; j < 4; ++j) {
            const int i_l = r * 4 + j;
            P3 a = lds[i_l * 64 + o_l];
            A2[(size_t)(i0 + i_l) * WL_O + o] = (v2f){a.nti, a.inv};
            W1[(size_t)(i0 + i_l) * WL_O + o] = a.w;
        }
    }
}

// Main: grid (O/64=16, B/16=32) = 512 blocks (2/CU), 1024 thr = 16 waves.
// Wave wid = i-sixteenth (32 i); covers all 16 b of the tile.
// XCD = gx mod 8 -> 2 param slabs per XCD's L2 (786 KB, resident).
__global__ __launch_bounds__(1024, 8) void wl_main(
    const float* __restrict__ x,
    const v2f* __restrict__ A2,
    const float* __restrict__ W1,
    float* __restrict__ out)
{
    __shared__ float smem[8192];                       // 32 KB: xT, then reduce

    const int tid  = threadIdx.x;
    const int lane = tid & 63;
    const int wid  = tid >> 6;                         // 0..15 = i-sixteenth
    const int o    = blockIdx.x * 64 + lane;
    const int b0   = blockIdx.y * 16;

    // ---- stage x^T once: xT[i*16 + b_l]; 4-way write conflicts, one-time ----
    {
        const int b_l = tid & 15;
        const int seg = tid >> 4;                      // 0..63 -> i in [seg*8,+8)
        const float* xg = &x[(size_t)(b0 + b_l) * WL_I + seg * 8];
        const float4 v0 = *reinterpret_cast<const float4*>(xg);
        const float4 v1 = *reinterpret_cast<const float4*>(xg + 4);
        const int base = seg * 8 * 16 + b_l;
        smem[base + 0 * 16] = v0.x;
        smem[base + 1 * 16] = v0.y;
        smem[base + 2 * 16] = v0.z;
        smem[base + 3 * 16] = v0.w;
        smem[base + 4 * 16] = v1.x;
        smem[base + 5 * 16] = v1.y;
        smem[base + 6 * 16] = v1.z;
        smem[base + 7 * 16] = v1.w;
    }
    __syncthreads();

    const v2f*   __restrict__ pA = A2 + (size_t)(wid * 32) * WL_O + o;
    const float* __restrict__ pW = W1 + (size_t)(wid * 32) * WL_O + o;
    const float* xrow = &smem[wid * 32 * 16];          // uniform per wave

    float acc[16] = {0.f,0.f,0.f,0.f, 0.f,0.f,0.f,0.f,
                     0.f,0.f,0.f,0.f, 0.f,0.f,0.f,0.f};

    #pragma unroll 4
    for (int ii = 0; ii < 32; ++ii) {
        const v2f   pa = pA[(size_t)ii * WL_O];        // {nti,inv} 512B/wave, indexed
        const float w  = pW[(size_t)ii * WL_O];        // w          256B/wave, indexed
        const float mwk = w * (-WL_IK);                // 1 v_mul (literal src0)
        const float nti = pa.x, inv = pa.y;
        const float4* xf = reinterpret_cast<const float4*>(xrow + ii * 16);
        // process 16 b in 4 chunks of 4 to keep register liveness short
        #pragma unroll
        for (int q = 0; q < 4; ++q) {
            const float4 xq = xf[q];                   // uniform LDS broadcast
            const float xs[4] = {xq.x, xq.y, xq.z, xq.w};
            #pragma unroll
            for (int j = 0; j < 4; ++j) {
                const int b = q * 4 + j;
                const float s = fmaf(xs[j], inv, nti);
                const float u = s * s;
                const float e = fast_exp2(-u);         // neg folds into trans src-mod
                const float v = fmaf(mwk, u, w);
                acc[b] = fmaf(v, e, acc[b]);
            }
        }
    }

    // ---- reduce over 16 i-waves: two phases of 8 b each ----
    __syncthreads();                                   // done reading xT
    #pragma unroll
    for (int k = 0; k < 8; ++k)                        // dump acc[0..7] (b_l 0..7)
        smem[(wid * 8 + k) * 64 + lane] = acc[k];      // lane-stride 4B: conflict-free
    __syncthreads();
    if (wid < 8) {                                     // wave w sums b_l = w
        float y = 0.f;
        #pragma unroll
        for (int src = 0; src < 16; ++src)
            y += smem[(src * 8 + wid) * 64 + lane];
        out[(size_t)(b0 + wid) * WL_O + o] = y;
    }
    __syncthreads();
    #pragma unroll
    for (int k = 0; k < 8; ++k)                        // dump acc[8..15] (b_l 8..15)
        smem[(wid * 8 + k) * 64 + lane] = acc[8 + k];
    __syncthreads();
    if (wid >= 8) {                                    // wave w sums b_l = w
        float y = 0.f;
        #pragma unroll
        for (int src = 0; src < 16; ++src)
            y += smem[(src * 8 + (wid - 8)) * 64 + lane];
        out[(size_t)(b0 + wid) * WL_O + o] = y;
    }
}

extern "C" void kernel_launch(void* const* d_in, const int* in_sizes, int n_in,
                              void* d_out, int out_size, void* d_ws, size_t ws_size,
                              hipStream_t stream) {
    const float* x           = (const float*)d_in[0];
    const float* translation = (const float*)d_in[1];
    const float* scale_raw   = (const float*)d_in[2];
    const float* weights     = (const float*)d_in[3];
    float*       out         = (float*)d_out;
    // workspace: A2 pairs {nti,inv} 4.19MB, then W1 floats 2.10MB (6.3MB total)
    v2f*   A2 = (v2f*)d_ws;
    float* W1 = (float*)((char*)d_ws + (size_t)WL_I * WL_O * sizeof(v2f));

    wl_prep<<<dim3(WL_O / 64, WL_I / 16), dim3(256), 0, stream>>>(
        translation, scale_raw, weights, A2, W1);

    wl_main<<<dim3(WL_O / 64, WL_B / 16), dim3(1024), 0, stream>>>(
        x, A2, W1, out);
}